// Round 18
// baseline (204.523 us; speedup 1.0000x reference)
//
#include <hip/hip_runtime.h>
#include <stdint.h>

// MHA: B=4, S=2048, D=1024, H=16, HD=64.
// Pipeline: f32->bf16 cvt (single fused kernel) -> fused QKV GEMM (bf16 MFMA,
// XCD-swizzled, LDS-coalesced Q/K/V epilogues, kt-unrolled dbuf) -> flash attn
// (R4-proven body, max3 softmax) -> output GEMM. Q pre-scaled by 0.125*log2(e).
//
// HARD-WON RULES:
//  - Never element-wise overwrite a register-resident f32x16 that flows through
//    MFMA inside a branch (R3/R9/R10 NaN'd).
//  - Never reorder MFMA clusters across (or within) the barrier/staging region
//    of the attn double-buffer loop (R11: replay-nondeterministic). attn frozen.
//  - Epilogue-only changes after a block-uniform barrier are safe (R14 proven).

typedef __bf16 bf16x8 __attribute__((ext_vector_type(8)));
typedef float f32x4 __attribute__((ext_vector_type(4)));
typedef float f32x16 __attribute__((ext_vector_type(16)));

__device__ __forceinline__ uint16_t f2bf(float f) {
  union { float f; uint32_t u; } c;
  c.f = f;
  uint32_t u = c.u + 0x7fffu + ((c.u >> 16) & 1u);  // RNE
  return (uint16_t)(u >> 16);
}

__device__ __forceinline__ float exp2_hw(float x) {
#if defined(__has_builtin) && __has_builtin(__builtin_amdgcn_exp2f)
  return __builtin_amdgcn_exp2f(x);
#else
  return exp2f(x);
#endif
}

__device__ __forceinline__ uint32_t cvt_pk_bf16(float lo, float hi) {
  uint32_t r;
  asm("v_cvt_pk_bf16_f32 %0, %1, %2" : "=v"(r) : "v"(lo), "v"(hi));
  return r;
}

__device__ __forceinline__ void gload16(const void* g, void* l) {
  __builtin_amdgcn_global_load_lds(
      (const __attribute__((address_space(1))) uint32_t*)g,
      (__attribute__((address_space(3))) uint32_t*)l,
      16, 0, 0);
}

// One kernel converts x (8192 blocks) + 4 weight matrices (1024 blocks each).
__global__ void cvt_all(const float* __restrict__ x, const float* __restrict__ w0,
                        const float* __restrict__ w1, const float* __restrict__ w2,
                        const float* __restrict__ w3, uint16_t* __restrict__ xo,
                        uint16_t* __restrict__ o0, uint16_t* __restrict__ o1,
                        uint16_t* __restrict__ o2, uint16_t* __restrict__ o3) {
  const int b = blockIdx.x;
  const float* src;
  uint16_t* dst;
  int i;
  if (b < 8192) {
    src = x; dst = xo; i = b * 256 + threadIdx.x;
  } else {
    const int wb = b - 8192;
    const int which = wb >> 10;
    src = (which == 0) ? w0 : (which == 1) ? w1 : (which == 2) ? w2 : w3;
    dst = (which == 0) ? o0 : (which == 1) ? o1 : (which == 2) ? o2 : o3;
    i = (wb & 1023) * 256 + threadIdx.x;
  }
  float4 v = reinterpret_cast<const float4*>(src)[i];
  union { uint16_t u[4]; uint2 d; } o;
  o.u[0] = f2bf(v.x); o.u[1] = f2bf(v.y);
  o.u[2] = f2bf(v.z); o.u[3] = f2bf(v.w);
  reinterpret_cast<uint2*>(dst)[i] = o.d;
}

// C[m,n] = sum_k A[m,k] * W[n,k] + bias  (torch Linear). A,W bf16 row-major K=1024.
// MODE 0: QKV fused (N=3072); MODE 1: out-proj (N=1024), fp32 out.
// V-blocks (which==2): LDS-transposed epilogue -> coalesced 256B [bh][hd][s] runs.
// Q/K-blocks: LDS ml-major restage -> 16B coalesced [bh][s][hd] stores
// (was 64 scalar 2B stores/thread).
template <int MODE>
__global__ __launch_bounds__(256, 3)
void gemm_nt(const uint16_t* __restrict__ A,
             const uint16_t* __restrict__ W0, const uint16_t* __restrict__ W1,
             const uint16_t* __restrict__ W2,
             const float* __restrict__ b0, const float* __restrict__ b1,
             const float* __restrict__ b2,
             uint16_t* __restrict__ oq, uint16_t* __restrict__ ok2,
             uint16_t* __restrict__ ovT, float* __restrict__ ofp) {
  __shared__ __align__(16) uint16_t S[4][128 * 32];  // staging dbuf + epilogue scratch
  uint16_t(*Alds)[128 * 32] = &S[0];
  uint16_t(*Blds)[128 * 32] = &S[2];

  const int tid = threadIdx.x;
  const int w = tid >> 6;
  const int l = tid & 63;
  const int wm = w >> 1, wn = w & 1;
  const int g = l >> 4, c16 = l & 15;

  // XCD-aware swizzle of the linear block id (nwg = 1536 or 512, both %8==0)
  const int nwg = gridDim.x * gridDim.y;
  const int lin = blockIdx.y * gridDim.x + blockIdx.x;
  const int swz = (lin & 7) * (nwg >> 3) + (lin >> 3);
  const int bxs = swz % gridDim.x;
  const int bys = swz / gridDim.x;
  const int brow = bys * 128;
  const int bcol = bxs * 128;

  const uint16_t* Wsel = W0;
  const float* bsel = b0;
  int which = 0;
  if (MODE == 0) {
    which = bcol >> 10;
    Wsel = (which == 0) ? W0 : ((which == 1) ? W1 : W2);
    bsel = (which == 0) ? b0 : ((which == 1) ? b1 : b2);
  }
  const int bw = bcol & 1023;

  const int srow = l >> 2;         // staging: row-within-16 (chunk c adds c*16)
  const int scol = (l & 3) * 8;    // staging: col (8 bf16 = 16B per lane)

  f32x4 acc[4][4];
#pragma unroll
  for (int i = 0; i < 4; ++i)
#pragma unroll
    for (int j = 0; j < 4; ++j) acc[i][j] = {0.f, 0.f, 0.f, 0.f};

  // prologue stage kt=0 into buf 0
#pragma unroll
  for (int i2 = 0; i2 < 2; ++i2) {
    const int c = 2 * w + i2;
    gload16(A + (size_t)(brow + c * 16 + srow) * 1024 + scol, &Alds[0][c * 512]);
    gload16(Wsel + (size_t)(bw + c * 16 + srow) * 1024 + scol, &Blds[0][c * 512]);
  }

  // kt loop unrolled x2 -> cur is compile-time (0,1); barrier sequence identical
  for (int kt0 = 0; kt0 < 32; kt0 += 2) {
#pragma unroll
    for (int sub = 0; sub < 2; ++sub) {
      const int kt = kt0 + sub;
      const int cur = sub;  // kt & 1
      __syncthreads();  // buf[cur] staged; all waves done reading buf[cur^1]
      if (kt + 1 < 32) {
        const int k0 = (kt + 1) * 32;
#pragma unroll
        for (int i2 = 0; i2 < 2; ++i2) {
          const int c = 2 * w + i2;
          gload16(A + (size_t)(brow + c * 16 + srow) * 1024 + k0 + scol,
                  &Alds[cur ^ 1][c * 512]);
          gload16(Wsel + (size_t)(bw + c * 16 + srow) * 1024 + k0 + scol,
                  &Blds[cur ^ 1][c * 512]);
        }
      }
      bf16x8 af[4], bfr[4];
#pragma unroll
      for (int i = 0; i < 4; ++i)
        af[i] = *reinterpret_cast<const bf16x8*>(
            &Alds[cur][(wm * 64 + i * 16 + c16) * 32 + g * 8]);
#pragma unroll
      for (int j = 0; j < 4; ++j)
        bfr[j] = *reinterpret_cast<const bf16x8*>(
            &Blds[cur][(wn * 64 + j * 16 + c16) * 32 + g * 8]);
#pragma unroll
      for (int i = 0; i < 4; ++i)
#pragma unroll
        for (int j = 0; j < 4; ++j)
          acc[i][j] = __builtin_amdgcn_mfma_f32_16x16x32_bf16(af[i], bfr[j],
                                                              acc[i][j], 0, 0, 0);
    }
  }

  // epilogue: D row = 4*(l>>4)+reg, col = l&15 (m89-verified)
  if (MODE == 0 && which == 2) {
    // ---- V: transpose via LDS, then coalesced [bh][hd][s] 16B stores ----
    __syncthreads();  // all waves done with staging buffers
    uint8_t* T = reinterpret_cast<uint8_t*>(&S[0][0]);  // 32KB = 128x128 bf16
#pragma unroll
    for (int i = 0; i < 4; ++i) {
#pragma unroll
      for (int j = 0; j < 4; ++j) {
        const int nl = wn * 64 + j * 16 + c16;      // v-col within tile
        const float bias = bsel[bw + nl];
        const int ml0 = wm * 64 + i * 16 + g * 4;   // s within tile (4-run)
        const uint32_t lo = cvt_pk_bf16(acc[i][j][0] + bias, acc[i][j][1] + bias);
        const uint32_t hi2 = cvt_pk_bf16(acc[i][j][2] + bias, acc[i][j][3] + bias);
        const int byt = (nl * 256 + ml0 * 2) ^ ((nl & 7) << 4);
        *reinterpret_cast<uint32_t*>(T + byt) = lo;
        *reinterpret_cast<uint32_t*>(T + byt + 4) = hi2;
      }
    }
    __syncthreads();
    const int b = brow >> 11;
    const int sbase = brow & 2047;
#pragma unroll
    for (int p = 0; p < 8; ++p) {
      const int idx = p * 256 + tid;
      const int nl = idx >> 4;
      const int mlb = (idx & 15) * 16;  // byte offset of 8-u16 s-run
      const int byt = (nl * 256 + mlb) ^ ((nl & 7) << 4);
      const uint4 vv = *reinterpret_cast<const uint4*>(T + byt);
      const int col = bw + nl;
      const size_t bh = (size_t)(b * 16 + (col >> 6));
      const int hd = col & 63;
      const int s0 = sbase + (idx & 15) * 8;
      *reinterpret_cast<uint4*>(&ovT[(bh * 64 + hd) * 2048 + s0]) = vv;
    }
  } else if (MODE == 0) {
    // ---- Q/K: restage ml-major in LDS, then 16B coalesced [bh][s][hd] stores
    __syncthreads();  // all waves done with staging buffers
    uint8_t* T = reinterpret_cast<uint8_t*>(&S[0][0]);  // 32KB = 128x128 bf16
    const float qscale = (which == 0) ? 0.18033688011112042f : 1.0f;
#pragma unroll
    for (int i = 0; i < 4; ++i) {
#pragma unroll
      for (int j = 0; j < 4; ++j) {
        const int nl = wn * 64 + j * 16 + c16;      // hd-col within tile
        const float bias = bsel[bw + nl];
#pragma unroll
        for (int r = 0; r < 4; ++r) {
          const int ml = wm * 64 + i * 16 + g * 4 + r;  // s-row within tile
          const uint16_t h16 = f2bf((acc[i][j][r] + bias) * qscale);
          const int byt = (ml * 256 + nl * 2) ^ ((ml & 7) << 4);
          *reinterpret_cast<uint16_t*>(T + byt) = h16;
        }
      }
    }
    __syncthreads();
    uint16_t* const dst = (which == 0) ? oq : ok2;
    const int b = brow >> 11;
    const int sbase = brow & 2047;
#pragma unroll
    for (int p = 0; p < 8; ++p) {
      const int idx = p * 256 + tid;          // 2048 16B-chunks
      const int ml = idx >> 4;
      const int chunk = idx & 15;             // 8-element hd run
      const int byt = (ml * 256 + chunk * 16) ^ ((ml & 7) << 4);
      const uint4 vv = *reinterpret_cast<const uint4*>(T + byt);
      const int col = bw + chunk * 8;
      const size_t bh = (size_t)(b * 16 + (col >> 6));
      const int hd = col & 63;
      const int s = sbase + ml;
      *reinterpret_cast<uint4*>(&dst[(bh * 2048 + s) * 64 + hd]) = vv;
    }
  } else {
#pragma unroll
    for (int i = 0; i < 4; ++i) {
#pragma unroll
      for (int j = 0; j < 4; ++j) {
        const int n = bcol + wn * 64 + j * 16 + c16;
        const float bias = bsel[n & 1023];
#pragma unroll
        for (int r = 0; r < 4; ++r) {
          const int m = brow + wm * 64 + i * 16 + g * 4 + r;
          ofp[(size_t)m * 1024 + n] = acc[i][j][r] + bias;
        }
      }
    }
  }
}

// Flash attention — R4 body + max3 softmax (post-timing-proven, ~108us). FROZEN.
// Grid (bh=64, qb=8), 4 waves, wave owns 64 q-rows (2 groups of 32).
__global__ __launch_bounds__(256, 2)
void attn_fwd(const uint16_t* __restrict__ Q, const uint16_t* __restrict__ K,
              const uint16_t* __restrict__ VT, uint16_t* __restrict__ CTX) {
  __shared__ __align__(16) uint16_t Klds[2][64 * 64];
  __shared__ __align__(16) uint16_t Vlds[2][64 * 64];

  const int tid = threadIdx.x;
  const int w = tid >> 6;
  const int l = tid & 63;
  const int hi = l >> 5, q5 = l & 31;
  const int bh = blockIdx.x;
  const int qb = blockIdx.y;
  const int qrow_base = qb * 256 + w * 64;

  // kappa: D-row r holds key kappa(r); bijective bit-swap of bits 2 and 3
  const int kappa = (q5 & 3) | (((q5 >> 3) & 1) << 2) | (((q5 >> 2) & 1) << 3) |
                    ((q5 >> 4) << 4);

  // Q fragments: B-operand cols = q5, k = 8*hi + j at hd-chunk 16*ks
  bf16x8 qf[2][4];
#pragma unroll
  for (int grp = 0; grp < 2; ++grp) {
    const uint16_t* qp =
        Q + ((size_t)bh * 2048 + qrow_base + grp * 32 + q5) * 64 + 8 * hi;
#pragma unroll
    for (int ks = 0; ks < 4; ++ks)
      qf[grp][ks] = *reinterpret_cast<const bf16x8*>(qp + 16 * ks);
  }

  f32x16 ctx[2][2];  // [grp][hd-block]
#pragma unroll
  for (int grp = 0; grp < 2; ++grp)
#pragma unroll
    for (int hb = 0; hb < 2; ++hb)
#pragma unroll
      for (int e = 0; e < 16; ++e) ctx[grp][hb][e] = 0.f;
  float M[2] = {-1024.0f, -1024.0f};  // finite sentinel -> first tile rescales
  float L[2] = {0.f, 0.f};

  auto stage = [&](int kt, int buf) {
#pragma unroll
    for (int i2 = 0; i2 < 2; ++i2) {
      const int c = 2 * w + i2;
      const int lb = c * 1024 + l * 16;          // linear dest byte in 8KB tile
      const int row = lb >> 7;                   // 128B rows
      const int so = lb ^ ((row & 7) << 4);      // inverse-swizzled source byte
      const int colel = (so & 127) >> 1;
      gload16(K + ((size_t)bh * 2048 + kt * 64 + row) * 64 + colel,
              &Klds[buf][c * 512]);
      gload16(VT + ((size_t)bh * 64 + row) * 2048 + kt * 64 + colel,
              &Vlds[buf][c * 512]);
    }
  };

  // precomputed swizzled in-row byte offsets
  int koff[4], voff[2][2];  // koff[ks]; voff[half][ks2]
#pragma unroll
  for (int ks = 0; ks < 4; ++ks)
    koff[ks] = (32 * ks + 16 * hi) ^ ((kappa & 7) << 4);
#pragma unroll
  for (int half = 0; half < 2; ++half)
#pragma unroll
    for (int ks2 = 0; ks2 < 2; ++ks2)
      voff[half][ks2] = (half * 64 + 32 * ks2 + 16 * hi) ^ ((q5 & 7) << 4);

  stage(0, 0);

  for (int kt = 0; kt < 32; ++kt) {
    __syncthreads();
    const int cur = kt & 1;
    if (kt + 1 < 32) stage(kt + 1, cur ^ 1);
    const uint8_t* kb = reinterpret_cast<const uint8_t*>(&Klds[cur][0]);
    const uint8_t* vb = reinterpret_cast<const uint8_t*>(&Vlds[cur][0]);

#pragma unroll
    for (int half = 0; half < 2; ++half) {
      // K A-frags: row = half*32 + kappa, 4 hd-chunks
      bf16x8 kf[4];
      const int krow = half * 32 + kappa;
#pragma unroll
      for (int ks = 0; ks < 4; ++ks)
        kf[ks] = *reinterpret_cast<const bf16x8*>(kb + krow * 128 + koff[ks]);
      // V A-frags: row = 32*hb + q5, keys 16*ks2(+half*32)
      bf16x8 vf[2][2];
#pragma unroll
      for (int hb = 0; hb < 2; ++hb) {
        const int vrow = 32 * hb + q5;
#pragma unroll
        for (int ks2 = 0; ks2 < 2; ++ks2)
          vf[hb][ks2] = *reinterpret_cast<const bf16x8*>(
              vb + vrow * 128 + voff[half][ks2]);
      }

#pragma unroll
      for (int grp = 0; grp < 2; ++grp) {
        // QK^T: D[key32][q32], C-init = -M folds running-max subtraction
        const float negM = -M[grp];
        f32x16 sc;
#pragma unroll
        for (int e = 0; e < 16; ++e) sc[e] = negM;
        __builtin_amdgcn_s_setprio(1);
#pragma unroll
        for (int ks = 0; ks < 4; ++ks)
          sc = __builtin_amdgcn_mfma_f32_32x32x16_bf16(kf[ks], qf[grp][ks], sc,
                                                       0, 0, 0);
        __builtin_amdgcn_s_setprio(0);

        // row max: max3-fusable triples (5 v_max3 + 4 v_max), then lane pair
        float m0 = fmaxf(fmaxf(sc[0], sc[1]), sc[2]);
        float m1 = fmaxf(fmaxf(sc[3], sc[4]), sc[5]);
        float m2 = fmaxf(fmaxf(sc[6], sc[7]), sc[8]);
        float m3 = fmaxf(fmaxf(sc[9], sc[10]), sc[11]);
        float m4 = fmaxf(fmaxf(sc[12], sc[13]), sc[14]);
        float mloc = fmaxf(fmaxf(fmaxf(m0, m1), fmaxf(m2, m3)),
                           fmaxf(m4, sc[15]));
        mloc = fmaxf(mloc, __shfl_xor(mloc, 32));

        float p[16];
        if (__any(mloc > 8.0f)) {  // defer-max: rescale only on >2^8 growth
          const float delta = fmaxf(mloc, 0.0f);
          const float corr = exp2_hw(-delta);
          M[grp] += delta;
          L[grp] *= corr;
#pragma unroll
          for (int hb = 0; hb < 2; ++hb)
#pragma unroll
            for (int e = 0; e < 16; ++e) ctx[grp][hb][e] *= corr;
#pragma unroll
          for (int e = 0; e < 16; ++e) p[e] = exp2_hw(sc[e] - delta);
        } else {
#pragma unroll
          for (int e = 0; e < 16; ++e) p[e] = exp2_hw(sc[e]);
        }

        L[grp] += ((p[0] + p[1]) + (p[2] + p[3])) +
                  ((p[4] + p[5]) + (p[6] + p[7])) +
                  ((p[8] + p[9]) + (p[10] + p[11])) +
                  ((p[12] + p[13]) + (p[14] + p[15]));

        // pack P: reg r <-> key 16*(r>>3) + 8*hi + (r&7), already B-frag order
        union { uint32_t u[4]; bf16x8 v; } pa0, pa1;
        pa0.u[0] = cvt_pk_bf16(p[0], p[1]);
        pa0.u[1] = cvt_pk_bf16(p[2], p[3]);
        pa0.u[2] = cvt_pk_bf16(p[4], p[5]);
        pa0.u[3] = cvt_pk_bf16(p[6], p[7]);
        pa1.u[0] = cvt_pk_bf16(p[8], p[9]);
        pa1.u[1] = cvt_pk_bf16(p[10], p[11]);
        pa1.u[2] = cvt_pk_bf16(p[12], p[13]);
        pa1.u[3] = cvt_pk_bf16(p[14], p[15]);

        __builtin_amdgcn_s_setprio(1);
#pragma unroll
        for (int hb = 0; hb < 2; ++hb) {
          ctx[grp][hb] = __builtin_amdgcn_mfma_f32_32x32x16_bf16(
              vf[hb][0], pa0.v, ctx[grp][hb], 0, 0, 0);
          ctx[grp][hb] = __builtin_amdgcn_mfma_f32_32x32x16_bf16(
              vf[hb][1], pa1.v, ctx[grp][hb], 0, 0, 0);
        }
        __builtin_amdgcn_s_setprio(0);
      }
    }
  }

  // finalize: L reduce across lane pair, normalize, store
  const int b = bh >> 4, h = bh & 15;
#pragma unroll
  for (int grp = 0; grp < 2; ++grp) {
    float Lt = L[grp] + __shfl_xor(L[grp], 32);
    const float inv = 1.0f / Lt;
    const int s = qrow_base + grp * 32 + q5;
#pragma unroll
    for (int hb = 0; hb < 2; ++hb) {
#pragma unroll
      for (int t = 0; t < 4; ++t) {
        // regs 4t..4t+3 -> hd = 32*hb + 8*t + 4*hi + (0..3)
        uint2 st;
        st.x = cvt_pk_bf16(ctx[grp][hb][4 * t] * inv,
                           ctx[grp][hb][4 * t + 1] * inv);
        st.y = cvt_pk_bf16(ctx[grp][hb][4 * t + 2] * inv,
                           ctx[grp][hb][4 * t + 3] * inv);
        *reinterpret_cast<uint2*>(
            &CTX[((size_t)b * 2048 + s) * 1024 + h * 64 + hb * 32 + t * 8 +
                 hi * 4]) = st;
      }
    }
  }
}

extern "C" void kernel_launch(void* const* d_in, const int* in_sizes, int n_in,
                              void* d_out, int out_size, void* d_ws,
                              size_t ws_size, hipStream_t stream) {
  (void)in_sizes; (void)n_in; (void)out_size; (void)ws_size;
  const float* x = (const float*)d_in[0];
  const float* wq = (const float*)d_in[1];
  const float* bq = (const float*)d_in[2];
  const float* wk = (const float*)d_in[3];
  const float* bk = (const float*)d_in[4];
  const float* wv = (const float*)d_in[5];
  const float* bv = (const float*)d_in[6];
  const float* wo = (const float*)d_in[7];
  const float* bo = (const float*)d_in[8];
  float* out = (float*)d_out;

  // ws layout (88 MB total)
  uint8_t* ws = (uint8_t*)d_ws;
  uint16_t* xb   = (uint16_t*)(ws + 0);                       // 16 MB  x bf16 [8192][1024]
  uint16_t* wqb  = (uint16_t*)(ws + 16777216);                // 2 MB each
  uint16_t* wkb  = (uint16_t*)(ws + 16777216 + 2097152);
  uint16_t* wvb  = (uint16_t*)(ws + 16777216 + 2 * 2097152);
  uint16_t* wob  = (uint16_t*)(ws + 16777216 + 3 * 2097152);
  uint16_t* qws  = (uint16_t*)(ws + 25165824);                // 16 MB [bh][s][hd]
  uint16_t* kws  = (uint16_t*)(ws + 25165824 + 16777216);     // 16 MB [bh][s][hd]
  uint16_t* vtws = (uint16_t*)(ws + 25165824 + 2 * 16777216); // 16 MB [bh][hd][s]
  uint16_t* ctxw = (uint16_t*)(ws + 25165824 + 3 * 16777216); // 16 MB [b][s][1024]

  cvt_all<<<12288, 256, 0, stream>>>(x, wq, wk, wv, wo, xb, wqb, wkb, wvb, wob);

  gemm_nt<0><<<dim3(24, 64), 256, 0, stream>>>(
      xb, wqb, wkb, wvb, bq, bk, bv, qws, kws, vtws, nullptr);
  attn_fwd<<<dim3(64, 8), 256, 0, stream>>>(qws, kws, vtws, ctxw);
  gemm_nt<1><<<dim3(8, 64), 256, 0, stream>>>(
      ctxw, wob, nullptr, nullptr, bo, nullptr, nullptr, nullptr, nullptr,
      nullptr, out);
}

// Round 19
// 203.837 us; speedup vs baseline: 1.0034x; 1.0034x over previous
//
#include <hip/hip_runtime.h>
#include <stdint.h>

// MHA: B=4, S=2048, D=1024, H=16, HD=64.
// Pipeline: f32->bf16 cvt (single fused kernel) -> fused QKV GEMM (bf16 MFMA,
// XCD-swizzled, LDS-transposed V epilogue, kt-unrolled dbuf) -> flash attn
// (R4-proven body, max3 softmax) -> output GEMM. Q pre-scaled by 0.125*log2(e).
// == R16 champion configuration (203.9 us measured); R17's Q/K LDS epilogue
// was neutral-negative and is reverted. ==
//
// HARD-WON RULES:
//  - Never element-wise overwrite a register-resident f32x16 that flows through
//    MFMA inside a branch (R3/R9/R10 NaN'd).
//  - Never reorder MFMA clusters across (or within) the barrier/staging region
//    of the attn double-buffer loop (R11: replay-nondeterministic). attn frozen.
//  - Epilogue-only changes after a block-uniform barrier are safe, but only
//    profitable when they fix real write amplification (V: yes; Q/K: no).

typedef __bf16 bf16x8 __attribute__((ext_vector_type(8)));
typedef float f32x4 __attribute__((ext_vector_type(4)));
typedef float f32x16 __attribute__((ext_vector_type(16)));

__device__ __forceinline__ uint16_t f2bf(float f) {
  union { float f; uint32_t u; } c;
  c.f = f;
  uint32_t u = c.u + 0x7fffu + ((c.u >> 16) & 1u);  // RNE
  return (uint16_t)(u >> 16);
}

__device__ __forceinline__ float exp2_hw(float x) {
#if defined(__has_builtin) && __has_builtin(__builtin_amdgcn_exp2f)
  return __builtin_amdgcn_exp2f(x);
#else
  return exp2f(x);
#endif
}

__device__ __forceinline__ uint32_t cvt_pk_bf16(float lo, float hi) {
  uint32_t r;
  asm("v_cvt_pk_bf16_f32 %0, %1, %2" : "=v"(r) : "v"(lo), "v"(hi));
  return r;
}

__device__ __forceinline__ void gload16(const void* g, void* l) {
  __builtin_amdgcn_global_load_lds(
      (const __attribute__((address_space(1))) uint32_t*)g,
      (__attribute__((address_space(3))) uint32_t*)l,
      16, 0, 0);
}

// One kernel converts x (8192 blocks) + 4 weight matrices (1024 blocks each).
__global__ void cvt_all(const float* __restrict__ x, const float* __restrict__ w0,
                        const float* __restrict__ w1, const float* __restrict__ w2,
                        const float* __restrict__ w3, uint16_t* __restrict__ xo,
                        uint16_t* __restrict__ o0, uint16_t* __restrict__ o1,
                        uint16_t* __restrict__ o2, uint16_t* __restrict__ o3) {
  const int b = blockIdx.x;
  const float* src;
  uint16_t* dst;
  int i;
  if (b < 8192) {
    src = x; dst = xo; i = b * 256 + threadIdx.x;
  } else {
    const int wb = b - 8192;
    const int which = wb >> 10;
    src = (which == 0) ? w0 : (which == 1) ? w1 : (which == 2) ? w2 : w3;
    dst = (which == 0) ? o0 : (which == 1) ? o1 : (which == 2) ? o2 : o3;
    i = (wb & 1023) * 256 + threadIdx.x;
  }
  float4 v = reinterpret_cast<const float4*>(src)[i];
  union { uint16_t u[4]; uint2 d; } o;
  o.u[0] = f2bf(v.x); o.u[1] = f2bf(v.y);
  o.u[2] = f2bf(v.z); o.u[3] = f2bf(v.w);
  reinterpret_cast<uint2*>(dst)[i] = o.d;
}

// C[m,n] = sum_k A[m,k] * W[n,k] + bias  (torch Linear). A,W bf16 row-major K=1024.
// MODE 0: QKV fused (N=3072); MODE 1: out-proj (N=1024), fp32 out.
// V-blocks (which==2): LDS-transposed epilogue -> coalesced 256B [bh][hd][s] runs.
// kt loop unrolled x2: compile-time dbuf indices (barrier order unchanged).
template <int MODE>
__global__ __launch_bounds__(256, 3)
void gemm_nt(const uint16_t* __restrict__ A,
             const uint16_t* __restrict__ W0, const uint16_t* __restrict__ W1,
             const uint16_t* __restrict__ W2,
             const float* __restrict__ b0, const float* __restrict__ b1,
             const float* __restrict__ b2,
             uint16_t* __restrict__ oq, uint16_t* __restrict__ ok2,
             uint16_t* __restrict__ ovT, float* __restrict__ ofp) {
  __shared__ __align__(16) uint16_t S[4][128 * 32];  // staging dbuf + transpose scratch
  uint16_t(*Alds)[128 * 32] = &S[0];
  uint16_t(*Blds)[128 * 32] = &S[2];

  const int tid = threadIdx.x;
  const int w = tid >> 6;
  const int l = tid & 63;
  const int wm = w >> 1, wn = w & 1;
  const int g = l >> 4, c16 = l & 15;

  // XCD-aware swizzle of the linear block id (nwg = 1536 or 512, both %8==0)
  const int nwg = gridDim.x * gridDim.y;
  const int lin = blockIdx.y * gridDim.x + blockIdx.x;
  const int swz = (lin & 7) * (nwg >> 3) + (lin >> 3);
  const int bxs = swz % gridDim.x;
  const int bys = swz / gridDim.x;
  const int brow = bys * 128;
  const int bcol = bxs * 128;

  const uint16_t* Wsel = W0;
  const float* bsel = b0;
  int which = 0;
  if (MODE == 0) {
    which = bcol >> 10;
    Wsel = (which == 0) ? W0 : ((which == 1) ? W1 : W2);
    bsel = (which == 0) ? b0 : ((which == 1) ? b1 : b2);
  }
  const int bw = bcol & 1023;

  const int srow = l >> 2;         // staging: row-within-16 (chunk c adds c*16)
  const int scol = (l & 3) * 8;    // staging: col (8 bf16 = 16B per lane)

  f32x4 acc[4][4];
#pragma unroll
  for (int i = 0; i < 4; ++i)
#pragma unroll
    for (int j = 0; j < 4; ++j) acc[i][j] = {0.f, 0.f, 0.f, 0.f};

  // prologue stage kt=0 into buf 0
#pragma unroll
  for (int i2 = 0; i2 < 2; ++i2) {
    const int c = 2 * w + i2;
    gload16(A + (size_t)(brow + c * 16 + srow) * 1024 + scol, &Alds[0][c * 512]);
    gload16(Wsel + (size_t)(bw + c * 16 + srow) * 1024 + scol, &Blds[0][c * 512]);
  }

  // kt loop unrolled x2 -> cur is compile-time (0,1); barrier sequence identical
  for (int kt0 = 0; kt0 < 32; kt0 += 2) {
#pragma unroll
    for (int sub = 0; sub < 2; ++sub) {
      const int kt = kt0 + sub;
      const int cur = sub;  // kt & 1
      __syncthreads();  // buf[cur] staged; all waves done reading buf[cur^1]
      if (kt + 1 < 32) {
        const int k0 = (kt + 1) * 32;
#pragma unroll
        for (int i2 = 0; i2 < 2; ++i2) {
          const int c = 2 * w + i2;
          gload16(A + (size_t)(brow + c * 16 + srow) * 1024 + k0 + scol,
                  &Alds[cur ^ 1][c * 512]);
          gload16(Wsel + (size_t)(bw + c * 16 + srow) * 1024 + k0 + scol,
                  &Blds[cur ^ 1][c * 512]);
        }
      }
      bf16x8 af[4], bfr[4];
#pragma unroll
      for (int i = 0; i < 4; ++i)
        af[i] = *reinterpret_cast<const bf16x8*>(
            &Alds[cur][(wm * 64 + i * 16 + c16) * 32 + g * 8]);
#pragma unroll
      for (int j = 0; j < 4; ++j)
        bfr[j] = *reinterpret_cast<const bf16x8*>(
            &Blds[cur][(wn * 64 + j * 16 + c16) * 32 + g * 8]);
#pragma unroll
      for (int i = 0; i < 4; ++i)
#pragma unroll
        for (int j = 0; j < 4; ++j)
          acc[i][j] = __builtin_amdgcn_mfma_f32_16x16x32_bf16(af[i], bfr[j],
                                                              acc[i][j], 0, 0, 0);
    }
  }

  // epilogue: D row = 4*(l>>4)+reg, col = l&15 (m89-verified)
  if (MODE == 0 && which == 2) {
    // ---- V: transpose via LDS, then coalesced [bh][hd][s] 16B stores ----
    __syncthreads();  // all waves done with staging buffers
    uint8_t* T = reinterpret_cast<uint8_t*>(&S[0][0]);  // 32KB = 128x128 bf16
#pragma unroll
    for (int i = 0; i < 4; ++i) {
#pragma unroll
      for (int j = 0; j < 4; ++j) {
        const int nl = wn * 64 + j * 16 + c16;      // v-col within tile
        const float bias = bsel[bw + nl];
        const int ml0 = wm * 64 + i * 16 + g * 4;   // s within tile (4-run)
        const uint32_t lo = cvt_pk_bf16(acc[i][j][0] + bias, acc[i][j][1] + bias);
        const uint32_t hi2 = cvt_pk_bf16(acc[i][j][2] + bias, acc[i][j][3] + bias);
        const int byt = (nl * 256 + ml0 * 2) ^ ((nl & 7) << 4);
        *reinterpret_cast<uint32_t*>(T + byt) = lo;
        *reinterpret_cast<uint32_t*>(T + byt + 4) = hi2;
      }
    }
    __syncthreads();
    const int b = brow >> 11;
    const int sbase = brow & 2047;
#pragma unroll
    for (int p = 0; p < 8; ++p) {
      const int idx = p * 256 + tid;
      const int nl = idx >> 4;
      const int mlb = (idx & 15) * 16;  // byte offset of 8-u16 s-run
      const int byt = (nl * 256 + mlb) ^ ((nl & 7) << 4);
      const uint4 vv = *reinterpret_cast<const uint4*>(T + byt);
      const int col = bw + nl;
      const size_t bh = (size_t)(b * 16 + (col >> 6));
      const int hd = col & 63;
      const int s0 = sbase + (idx & 15) * 8;
      *reinterpret_cast<uint4*>(&ovT[(bh * 64 + hd) * 2048 + s0]) = vv;
    }
  } else {
#pragma unroll
    for (int i = 0; i < 4; ++i) {
#pragma unroll
      for (int j = 0; j < 4; ++j) {
        const int n = bcol + wn * 64 + j * 16 + c16;
        const int nn = n & 1023;
        const float bias = bsel[nn];
#pragma unroll
        for (int r = 0; r < 4; ++r) {
          const int m = brow + wm * 64 + i * 16 + g * 4 + r;
          const float val = acc[i][j][r] + bias;
          if (MODE == 0) {
            const int s = m & 2047, b = m >> 11;
            const int h = nn >> 6, hd = nn & 63;
            const size_t bh = (size_t)(b * 16 + h);
            if (which == 0)
              oq[(bh * 2048 + s) * 64 + hd] = f2bf(val * 0.18033688011112042f);
            else
              ok2[(bh * 2048 + s) * 64 + hd] = f2bf(val);
          } else {
            ofp[(size_t)m * 1024 + n] = val;
          }
        }
      }
    }
  }
}

// Flash attention — R4 body + max3 softmax (post-timing-proven, ~108us). FROZEN.
// Grid (bh=64, qb=8), 4 waves, wave owns 64 q-rows (2 groups of 32).
__global__ __launch_bounds__(256, 2)
void attn_fwd(const uint16_t* __restrict__ Q, const uint16_t* __restrict__ K,
              const uint16_t* __restrict__ VT, uint16_t* __restrict__ CTX) {
  __shared__ __align__(16) uint16_t Klds[2][64 * 64];
  __shared__ __align__(16) uint16_t Vlds[2][64 * 64];

  const int tid = threadIdx.x;
  const int w = tid >> 6;
  const int l = tid & 63;
  const int hi = l >> 5, q5 = l & 31;
  const int bh = blockIdx.x;
  const int qb = blockIdx.y;
  const int qrow_base = qb * 256 + w * 64;

  // kappa: D-row r holds key kappa(r); bijective bit-swap of bits 2 and 3
  const int kappa = (q5 & 3) | (((q5 >> 3) & 1) << 2) | (((q5 >> 2) & 1) << 3) |
                    ((q5 >> 4) << 4);

  // Q fragments: B-operand cols = q5, k = 8*hi + j at hd-chunk 16*ks
  bf16x8 qf[2][4];
#pragma unroll
  for (int grp = 0; grp < 2; ++grp) {
    const uint16_t* qp =
        Q + ((size_t)bh * 2048 + qrow_base + grp * 32 + q5) * 64 + 8 * hi;
#pragma unroll
    for (int ks = 0; ks < 4; ++ks)
      qf[grp][ks] = *reinterpret_cast<const bf16x8*>(qp + 16 * ks);
  }

  f32x16 ctx[2][2];  // [grp][hd-block]
#pragma unroll
  for (int grp = 0; grp < 2; ++grp)
#pragma unroll
    for (int hb = 0; hb < 2; ++hb)
#pragma unroll
      for (int e = 0; e < 16; ++e) ctx[grp][hb][e] = 0.f;
  float M[2] = {-1024.0f, -1024.0f};  // finite sentinel -> first tile rescales
  float L[2] = {0.f, 0.f};

  auto stage = [&](int kt, int buf) {
#pragma unroll
    for (int i2 = 0; i2 < 2; ++i2) {
      const int c = 2 * w + i2;
      const int lb = c * 1024 + l * 16;          // linear dest byte in 8KB tile
      const int row = lb >> 7;                   // 128B rows
      const int so = lb ^ ((row & 7) << 4);      // inverse-swizzled source byte
      const int colel = (so & 127) >> 1;
      gload16(K + ((size_t)bh * 2048 + kt * 64 + row) * 64 + colel,
              &Klds[buf][c * 512]);
      gload16(VT + ((size_t)bh * 64 + row) * 2048 + kt * 64 + colel,
              &Vlds[buf][c * 512]);
    }
  };

  // precomputed swizzled in-row byte offsets
  int koff[4], voff[2][2];  // koff[ks]; voff[half][ks2]
#pragma unroll
  for (int ks = 0; ks < 4; ++ks)
    koff[ks] = (32 * ks + 16 * hi) ^ ((kappa & 7) << 4);
#pragma unroll
  for (int half = 0; half < 2; ++half)
#pragma unroll
    for (int ks2 = 0; ks2 < 2; ++ks2)
      voff[half][ks2] = (half * 64 + 32 * ks2 + 16 * hi) ^ ((q5 & 7) << 4);

  stage(0, 0);

  for (int kt = 0; kt < 32; ++kt) {
    __syncthreads();
    const int cur = kt & 1;
    if (kt + 1 < 32) stage(kt + 1, cur ^ 1);
    const uint8_t* kb = reinterpret_cast<const uint8_t*>(&Klds[cur][0]);
    const uint8_t* vb = reinterpret_cast<const uint8_t*>(&Vlds[cur][0]);

#pragma unroll
    for (int half = 0; half < 2; ++half) {
      // K A-frags: row = half*32 + kappa, 4 hd-chunks
      bf16x8 kf[4];
      const int krow = half * 32 + kappa;
#pragma unroll
      for (int ks = 0; ks < 4; ++ks)
        kf[ks] = *reinterpret_cast<const bf16x8*>(kb + krow * 128 + koff[ks]);
      // V A-frags: row = 32*hb + q5, keys 16*ks2(+half*32)
      bf16x8 vf[2][2];
#pragma unroll
      for (int hb = 0; hb < 2; ++hb) {
        const int vrow = 32 * hb + q5;
#pragma unroll
        for (int ks2 = 0; ks2 < 2; ++ks2)
          vf[hb][ks2] = *reinterpret_cast<const bf16x8*>(
              vb + vrow * 128 + voff[half][ks2]);
      }

#pragma unroll
      for (int grp = 0; grp < 2; ++grp) {
        // QK^T: D[key32][q32], C-init = -M folds running-max subtraction
        const float negM = -M[grp];
        f32x16 sc;
#pragma unroll
        for (int e = 0; e < 16; ++e) sc[e] = negM;
        __builtin_amdgcn_s_setprio(1);
#pragma unroll
        for (int ks = 0; ks < 4; ++ks)
          sc = __builtin_amdgcn_mfma_f32_32x32x16_bf16(kf[ks], qf[grp][ks], sc,
                                                       0, 0, 0);
        __builtin_amdgcn_s_setprio(0);

        // row max: max3-fusable triples (5 v_max3 + 4 v_max), then lane pair
        float m0 = fmaxf(fmaxf(sc[0], sc[1]), sc[2]);
        float m1 = fmaxf(fmaxf(sc[3], sc[4]), sc[5]);
        float m2 = fmaxf(fmaxf(sc[6], sc[7]), sc[8]);
        float m3 = fmaxf(fmaxf(sc[9], sc[10]), sc[11]);
        float m4 = fmaxf(fmaxf(sc[12], sc[13]), sc[14]);
        float mloc = fmaxf(fmaxf(fmaxf(m0, m1), fmaxf(m2, m3)),
                           fmaxf(m4, sc[15]));
        mloc = fmaxf(mloc, __shfl_xor(mloc, 32));

        float p[16];
        if (__any(mloc > 8.0f)) {  // defer-max: rescale only on >2^8 growth
          const float delta = fmaxf(mloc, 0.0f);
          const float corr = exp2_hw(-delta);
          M[grp] += delta;
          L[grp] *= corr;
#pragma unroll
          for (int hb = 0; hb < 2; ++hb)
#pragma unroll
            for (int e = 0; e < 16; ++e) ctx[grp][hb][e] *= corr;
#pragma unroll
          for (int e = 0; e < 16; ++e) p[e] = exp2_hw(sc[e] - delta);
        } else {
#pragma unroll
          for (int e = 0; e < 16; ++e) p[e] = exp2_hw(sc[e]);
        }

        L[grp] += ((p[0] + p[1]) + (p[2] + p[3])) +
                  ((p[4] + p[5]) + (p[6] + p[7])) +
                  ((p[8] + p[9]) + (p[10] + p[11])) +
                  ((p[12] + p[13]) + (p[14] + p[15]));

        // pack P: reg r <-> key 16*(r>>3) + 8*hi + (r&7), already B-frag order
        union { uint32_t u[4]; bf16x8 v; } pa0, pa1;
        pa0.u[0] = cvt_pk_bf16(p[0], p[1]);
        pa0.u[1] = cvt_pk_bf16(p[2], p[3]);
        pa0.u[2] = cvt_pk_bf16(p[4], p[5]);
        pa0.u[3] = cvt_pk_bf16(p[6], p[7]);
        pa1.u[0] = cvt_pk_bf16(p[8], p[9]);
        pa1.u[1] = cvt_pk_bf16(p[10], p[11]);
        pa1.u[2] = cvt_pk_bf16(p[12], p[13]);
        pa1.u[3] = cvt_pk_bf16(p[14], p[15]);

        __builtin_amdgcn_s_setprio(1);
#pragma unroll
        for (int hb = 0; hb < 2; ++hb) {
          ctx[grp][hb] = __builtin_amdgcn_mfma_f32_32x32x16_bf16(
              vf[hb][0], pa0.v, ctx[grp][hb], 0, 0, 0);
          ctx[grp][hb] = __builtin_amdgcn_mfma_f32_32x32x16_bf16(
              vf[hb][1], pa1.v, ctx[grp][hb], 0, 0, 0);
        }
        __builtin_amdgcn_s_setprio(0);
      }
    }
  }

  // finalize: L reduce across lane pair, normalize, store
  const int b = bh >> 4, h = bh & 15;
#pragma unroll
  for (int grp = 0; grp < 2; ++grp) {
    float Lt = L[grp] + __shfl_xor(L[grp], 32);
    const float inv = 1.0f / Lt;
    const int s = qrow_base + grp * 32 + q5;
#pragma unroll
    for (int hb = 0; hb < 2; ++hb) {
#pragma unroll
      for (int t = 0; t < 4; ++t) {
        // regs 4t..4t+3 -> hd = 32*hb + 8*t + 4*hi + (0..3)
        uint2 st;
        st.x = cvt_pk_bf16(ctx[grp][hb][4 * t] * inv,
                           ctx[grp][hb][4 * t + 1] * inv);
        st.y = cvt_pk_bf16(ctx[grp][hb][4 * t + 2] * inv,
                           ctx[grp][hb][4 * t + 3] * inv);
        *reinterpret_cast<uint2*>(
            &CTX[((size_t)b * 2048 + s) * 1024 + h * 64 + hb * 32 + t * 8 +
                 hi * 4]) = st;
      }
    }
  }
}

extern "C" void kernel_launch(void* const* d_in, const int* in_sizes, int n_in,
                              void* d_out, int out_size, void* d_ws,
                              size_t ws_size, hipStream_t stream) {
  (void)in_sizes; (void)n_in; (void)out_size; (void)ws_size;
  const float* x = (const float*)d_in[0];
  const float* wq = (const float*)d_in[1];
  const float* bq = (const float*)d_in[2];
  const float* wk = (const float*)d_in[3];
  const float* bk = (const float*)d_in[4];
  const float* wv = (const float*)d_in[5];
  const float* bv = (const float*)d_in[6];
  const float* wo = (const float*)d_in[7];
  const float* bo = (const float*)d_in[8];
  float* out = (float*)d_out;

  // ws layout (88 MB total)
  uint8_t* ws = (uint8_t*)d_ws;
  uint16_t* xb   = (uint16_t*)(ws + 0);                       // 16 MB  x bf16 [8192][1024]
  uint16_t* wqb  = (uint16_t*)(ws + 16777216);                // 2 MB each
  uint16_t* wkb  = (uint16_t*)(ws + 16777216 + 2097152);
  uint16_t* wvb  = (uint16_t*)(ws + 16777216 + 2 * 2097152);
  uint16_t* wob  = (uint16_t*)(ws + 16777216 + 3 * 2097152);
  uint16_t* qws  = (uint16_t*)(ws + 25165824);                // 16 MB [bh][s][hd]
  uint16_t* kws  = (uint16_t*)(ws + 25165824 + 16777216);     // 16 MB [bh][s][hd]
  uint16_t* vtws = (uint16_t*)(ws + 25165824 + 2 * 16777216); // 16 MB [bh][hd][s]
  uint16_t* ctxw = (uint16_t*)(ws + 25165824 + 3 * 16777216); // 16 MB [b][s][1024]

  cvt_all<<<12288, 256, 0, stream>>>(x, wq, wk, wv, wo, xb, wqb, wkb, wvb, wob);

  gemm_nt<0><<<dim3(24, 64), 256, 0, stream>>>(
      xb, wqb, wkb, wvb, bq, bk, bv, qws, kws, vtws, nullptr);
  attn_fwd<<<dim3(64, 8), 256, 0, stream>>>(qws, kws, vtws, ctxw);
  gemm_nt<1><<<dim3(8, 64), 256, 0, stream>>>(
      ctxw, wob, nullptr, nullptr, bo, nullptr, nullptr, nullptr, nullptr,
      nullptr, out);
}